// Round 3
// baseline (134.751 us; speedup 1.0000x reference)
//
#include <hip/hip_runtime.h>

#define N_SAMPLES 131072
#define N_EVENTS 128
#define N_ATOMS 32
#define ATOM_SIZE 512
#define LATENT 16
#define TIME_DIM 17
#define LAYERS 7
#define OUT_PER_BLOCK 1024   // 128 blocks x 1024 samples = 131072

// dot of a 16-element f32 row with 16 floats in LDS
__device__ __forceinline__ float dot16f(const float* __restrict__ wr,
                                        const float* __restrict__ x) {
    const float4* q = (const float4*)wr;
    float4 a = q[0], b = q[1], c = q[2], d = q[3];
    float s = 0.f;
    s += a.x * x[0]  + a.y * x[1]  + a.z * x[2]  + a.w * x[3];
    s += b.x * x[4]  + b.y * x[5]  + b.z * x[6]  + b.w * x[7];
    s += c.x * x[8]  + c.y * x[9]  + c.z * x[10] + c.w * x[11];
    s += d.x * x[12] + d.y * x[13] + d.z * x[14] + d.w * x[15];
    return s;
}

// Single fused kernel: 128 blocks x 256 threads, all co-resident (<= 256 CUs).
// Phase 1 (block b = event e): 7-layer tree walk -> times, x; dirac position
// p_e; atom coeffs; windowed/normalized/amp-scaled 512-sample atom -> wsA.
// Grid barrier (device-scope atomic, counter zeroed by host memset).
// Phase 2: block b gathers output range [b*1024, b*1024+1024):
//   out[k] = sum_e wsA[e][k - p_e], 0 <= k-p_e < 512.
__global__ __launch_bounds__(256) void fused_kernel(
    const float* __restrict__ base_latent,
    const float* __restrict__ to_time_W,
    const float* __restrict__ split_W,
    const float* __restrict__ split_b,
    const float* __restrict__ atoms,
    const float* __restrict__ to_atoms_W,
    const float* __restrict__ to_atoms_b,
    const float* __restrict__ to_amp_W,
    const float* __restrict__ to_amp_b,
    float* __restrict__ wsA,   // [128][512]
    int* __restrict__ wsP,     // [128]
    int* __restrict__ wsC,     // barrier counter (pre-zeroed)
    float* __restrict__ out)   // [131072]
{
    const int b = blockIdx.x;
    const int t = threadIdx.x;

    __shared__ float x_cur[LATENT];
    __shared__ float x_next[LATENT];
    __shared__ float times[2 * TIME_DIM];
    __shared__ float a32[N_ATOMS];
    __shared__ float s_amp, s_scale;
    __shared__ float wred[4];
    __shared__ int ev_p[N_EVENTS];
    __shared__ short ev_e[N_EVENTS];
    __shared__ int cnt;

    // ---------------- Phase 1: expand event b ----------------
    if (t < LATENT) x_cur[t] = base_latent[t];
    if (t < 2 * TIME_DIM) times[t] = 0.f;
    __syncthreads();

    for (int i = 0; i < LAYERS; ++i) {
        const int c = (b >> (6 - i)) & 1;
        if (t < LATENT) {
            const int row = c * LATENT + t;
            x_next[t] = split_b[i * 32 + row] +
                        dot16f(split_W + (i * 32 + row) * LATENT, x_cur);
        } else if (t < LATENT + 2 * TIME_DIM) {
            const int m = t - LATENT;                 // m = 2*d + j
            const int row = c * (2 * TIME_DIM) + m;
            times[m] += dot16f(to_time_W + (i * 68 + row) * LATENT, x_cur);
        }
        __syncthreads();
        if (t < LATENT) x_cur[t] = x_next[t];
        __syncthreads();
    }

    if (t == 0) {
        int p = 0;
#pragma unroll
        for (int d = 0; d < TIME_DIM; ++d) {
            if (times[2 * d + 1] > times[2 * d]) p |= 1 << (16 - d);
        }
        wsP[b] = p;
        s_amp = to_amp_b[0] + dot16f(to_amp_W, x_cur);
    }
    if (t < N_ATOMS) {
        a32[t] = to_atoms_b[t] + dot16f(to_atoms_W + t * LATENT, x_cur);
    }
    __syncthreads();

    // windowed atom: 2 columns per thread (cols t and t+256)
    float v0, v1, ss = 0.f;
    {
        float acc = 0.f;
#pragma unroll
        for (int m = 0; m < N_ATOMS; ++m) acc += a32[m] * atoms[m * ATOM_SIZE + t];
        float wnd = 0.54f - 0.46f * cosf((float)t * (float)(M_PI / 256.0));
        v0 = wnd * acc;
        ss += v0 * v0;

        acc = 0.f;
#pragma unroll
        for (int m = 0; m < N_ATOMS; ++m)
            acc += a32[m] * atoms[m * ATOM_SIZE + 256 + t];
        wnd = 0.54f - 0.46f * cosf((float)(t + 256) * (float)(M_PI / 256.0));
        v1 = wnd * acc;
        ss += v1 * v1;
    }
#pragma unroll
    for (int off = 32; off > 0; off >>= 1) ss += __shfl_xor(ss, off, 64);
    if ((t & 63) == 0) wred[t >> 6] = ss;
    __syncthreads();
    if (t == 0) {
        const float tot = wred[0] + wred[1] + wred[2] + wred[3];
        s_scale = s_amp / (sqrtf(tot) + 1e-8f);
    }
    __syncthreads();
    wsA[b * ATOM_SIZE + t]       = v0 * s_scale;
    wsA[b * ATOM_SIZE + 256 + t] = v1 * s_scale;

    // ---------------- Grid barrier (device scope) ----------------
    __threadfence();     // every wave: drain wsA/wsP writes to coherence point
    __syncthreads();
    if (t == 0) {
        __hip_atomic_fetch_add(wsC, 1, __ATOMIC_ACQ_REL, __HIP_MEMORY_SCOPE_AGENT);
        while (__hip_atomic_load(wsC, __ATOMIC_ACQUIRE, __HIP_MEMORY_SCOPE_AGENT)
               < (int)gridDim.x) {
            __builtin_amdgcn_s_sleep(8);
        }
    }
    __syncthreads();
    __threadfence();     // every wave: invalidate stale L1/L2 lines before reads

    // ---------------- Phase 2: gather [b*1024, b*1024+1024) ----------------
    if (t == 0) cnt = 0;
    __syncthreads();

    const int k0 = b * OUT_PER_BLOCK;
    if (t < N_EVENTS) {
        const int p = wsP[t];
        // segment [p, p+512) overlaps [k0, k0+1024) ?
        if (p + ATOM_SIZE > k0 && p < k0 + OUT_PER_BLOCK) {
            const int idx = atomicAdd(&cnt, 1);
            ev_p[idx] = p;
            ev_e[idx] = (short)t;
        }
    }
    __syncthreads();

    const int k = k0 + t * 4;
    float4 sum = make_float4(0.f, 0.f, 0.f, 0.f);
    const int n = cnt;
    for (int i = 0; i < n; ++i) {
        const float* __restrict__ src = wsA + (int)ev_e[i] * ATOM_SIZE;
        const int p = ev_p[i];
#pragma unroll
        for (int j = 0; j < 4; ++j) {
            const unsigned d = (unsigned)(k + j - p);
            if (d < (unsigned)ATOM_SIZE) (&sum.x)[j] += src[d];
        }
    }
    *(float4*)(out + k) = sum;
}

extern "C" void kernel_launch(void* const* d_in, const int* in_sizes, int n_in,
                              void* d_out, int out_size, void* d_ws, size_t ws_size,
                              hipStream_t stream)
{
    const float* base_latent = (const float*)d_in[0];
    const float* to_time_W   = (const float*)d_in[1];
    const float* split_W     = (const float*)d_in[2];
    const float* split_b     = (const float*)d_in[3];
    const float* atoms       = (const float*)d_in[4];
    const float* to_atoms_W  = (const float*)d_in[5];
    const float* to_atoms_b  = (const float*)d_in[6];
    const float* to_amp_W    = (const float*)d_in[7];
    const float* to_amp_b    = (const float*)d_in[8];

    float* wsA = (float*)d_ws;                                  // 256 KiB
    int*   wsP = (int*)((char*)d_ws + N_EVENTS * ATOM_SIZE * sizeof(float));
    int*   wsC = (int*)((char*)d_ws + N_EVENTS * ATOM_SIZE * sizeof(float) + 1024);

    // zero the barrier counter (ws is poisoned 0xAA before every launch)
    hipMemsetAsync(wsC, 0, sizeof(int), stream);

    fused_kernel<<<N_EVENTS, 256, 0, stream>>>(
        base_latent, to_time_W, split_W, split_b, atoms,
        to_atoms_W, to_atoms_b, to_amp_W, to_amp_b,
        wsA, wsP, wsC, (float*)d_out);
}

// Round 4
// 80.065 us; speedup vs baseline: 1.6830x; 1.6830x over previous
//
#include <hip/hip_runtime.h>

#define N_SAMPLES 131072
#define N_EVENTS 128
#define N_ATOMS 32
#define ATOM_SIZE 512
#define LATENT 16
#define TIME_DIM 17
#define LAYERS 7

// dot of a 16-element f32 row with 16 floats in LDS
__device__ __forceinline__ float dot16f(const float* __restrict__ wr,
                                        const float* __restrict__ x) {
    const float4* q = (const float4*)wr;
    float4 a = q[0], b = q[1], c = q[2], d = q[3];
    float s = 0.f;
    s += a.x * x[0]  + a.y * x[1]  + a.z * x[2]  + a.w * x[3];
    s += b.x * x[4]  + b.y * x[5]  + b.z * x[6]  + b.w * x[7];
    s += c.x * x[8]  + c.y * x[9]  + c.z * x[10] + c.w * x[11];
    s += d.x * x[12] + d.y * x[13] + d.z * x[14] + d.w * x[15];
    return s;
}

// One block per event (128 blocks x 256 threads). Walks the 7-layer binary
// tree path for event b (child bit c_i = (b>>(6-i))&1), accumulates time
// offsets, computes the hierarchical-dirac position p_b, atom coefficients,
// the windowed + L2-normalized + amp-scaled 512-sample atom, and scatters it
// into out[p_b .. p_b+512) with atomicAdd (out pre-zeroed by memset).
// No grid barrier, no d_ws: R3 showed device-scope fencing costs ~70us on
// 8 XCDs — a launch boundary (or atomics) is far cheaper.
__global__ __launch_bounds__(256) void expand_scatter_kernel(
    const float* __restrict__ base_latent,
    const float* __restrict__ to_time_W,
    const float* __restrict__ split_W,
    const float* __restrict__ split_b,
    const float* __restrict__ atoms,
    const float* __restrict__ to_atoms_W,
    const float* __restrict__ to_atoms_b,
    const float* __restrict__ to_amp_W,
    const float* __restrict__ to_amp_b,
    float* __restrict__ out)   // [131072], pre-zeroed
{
    const int b = blockIdx.x;
    const int t = threadIdx.x;

    __shared__ float x_cur[LATENT];
    __shared__ float x_next[LATENT];
    __shared__ float times[2 * TIME_DIM];
    __shared__ float a32[N_ATOMS];
    __shared__ float s_amp, s_scale;
    __shared__ float wred[4];
    __shared__ int s_p;

    if (t < LATENT) x_cur[t] = base_latent[t];
    if (t < 2 * TIME_DIM) times[t] = 0.f;
    __syncthreads();

    // --- 7-layer tree walk (50 parallel 16-dots per layer) ---
    for (int i = 0; i < LAYERS; ++i) {
        const int c = (b >> (6 - i)) & 1;
        if (t < LATENT) {
            const int row = c * LATENT + t;
            x_next[t] = split_b[i * 32 + row] +
                        dot16f(split_W + (i * 32 + row) * LATENT, x_cur);
        } else if (t < LATENT + 2 * TIME_DIM) {
            const int m = t - LATENT;                  // m = 2*d + j
            const int row = c * (2 * TIME_DIM) + m;
            times[m] += dot16f(to_time_W + (i * 68 + row) * LATENT, x_cur);
        }
        __syncthreads();
        if (t < LATENT) x_cur[t] = x_next[t];
        __syncthreads();
    }

    // --- dirac position p_b and amplitude ---
    if (t == 0) {
        int p = 0;
#pragma unroll
        for (int d = 0; d < TIME_DIM; ++d) {
            if (times[2 * d + 1] > times[2 * d]) p |= 1 << (16 - d);
        }
        s_p = p;
        s_amp = to_amp_b[0] + dot16f(to_amp_W, x_cur);
    }
    // --- atom coefficients ---
    if (t < N_ATOMS) {
        a32[t] = to_atoms_b[t] + dot16f(to_atoms_W + t * LATENT, x_cur);
    }
    __syncthreads();

    // --- windowed atom: 2 columns per thread (cols t and t+256) ---
    float v0, v1, ss = 0.f;
    {
        float acc = 0.f;
#pragma unroll
        for (int m = 0; m < N_ATOMS; ++m) acc += a32[m] * atoms[m * ATOM_SIZE + t];
        float wnd = 0.54f - 0.46f * cosf((float)t * (float)(M_PI / 256.0));
        v0 = wnd * acc;
        ss += v0 * v0;

        acc = 0.f;
#pragma unroll
        for (int m = 0; m < N_ATOMS; ++m)
            acc += a32[m] * atoms[m * ATOM_SIZE + 256 + t];
        wnd = 0.54f - 0.46f * cosf((float)(t + 256) * (float)(M_PI / 256.0));
        v1 = wnd * acc;
        ss += v1 * v1;
    }
    // block reduce of sum-of-squares (4 waves)
#pragma unroll
    for (int off = 32; off > 0; off >>= 1) ss += __shfl_xor(ss, off, 64);
    if ((t & 63) == 0) wred[t >> 6] = ss;
    __syncthreads();
    if (t == 0) {
        const float tot = wred[0] + wred[1] + wred[2] + wred[3];
        s_scale = s_amp / (sqrtf(tot) + 1e-8f);
    }
    __syncthreads();

    // --- scatter into out[p .. p+512), clipped to N_SAMPLES ---
    const int p = s_p;
    const float scale = s_scale;
    const int k0 = p + t;
    const int k1 = p + 256 + t;
    if (k0 < N_SAMPLES) atomicAdd(out + k0, v0 * scale);
    if (k1 < N_SAMPLES) atomicAdd(out + k1, v1 * scale);
}

extern "C" void kernel_launch(void* const* d_in, const int* in_sizes, int n_in,
                              void* d_out, int out_size, void* d_ws, size_t ws_size,
                              hipStream_t stream)
{
    const float* base_latent = (const float*)d_in[0];
    const float* to_time_W   = (const float*)d_in[1];
    const float* split_W     = (const float*)d_in[2];
    const float* split_b     = (const float*)d_in[3];
    const float* atoms       = (const float*)d_in[4];
    const float* to_atoms_W  = (const float*)d_in[5];
    const float* to_atoms_b  = (const float*)d_in[6];
    const float* to_amp_W    = (const float*)d_in[7];
    const float* to_amp_b    = (const float*)d_in[8];

    // d_out is poisoned 0xAA before every launch — zero it, then scatter-add.
    hipMemsetAsync(d_out, 0, (size_t)out_size * sizeof(float), stream);

    expand_scatter_kernel<<<N_EVENTS, 256, 0, stream>>>(
        base_latent, to_time_W, split_W, split_b, atoms,
        to_atoms_W, to_atoms_b, to_amp_W, to_amp_b, (float*)d_out);
}